// Round 9
// baseline (166.546 us; speedup 1.0000x reference)
//
#include <hip/hip_runtime.h>
#include <math.h>

#define N_TOTAL 8192
#define BHALF   4096
#define KDIM    128
#define NTILE   64          // 8192 / 128 tile grid
#define NTRI    2080        // 64*65/2 triangular tiles
#define NBLK_PW 512         // persistent blocks, exactly 2 per CU

typedef __bf16 bf16x8 __attribute__((ext_vector_type(8)));
typedef __bf16 bf16x2 __attribute__((ext_vector_type(2)));
typedef float  f32x4  __attribute__((ext_vector_type(4)));
typedef unsigned u32x2 __attribute__((ext_vector_type(2)));

// async global->LDS, 16B per lane; LDS dest must be lane-contiguous.
#define GLOAD_LDS16(GSRC, LDST)                                                \
    __builtin_amdgcn_global_load_lds(                                          \
        (const __attribute__((address_space(1))) void*)(GSRC),                 \
        (__attribute__((address_space(3))) void*)(LDST), 16, 0, 0)

// butterfly-add via DPP (VALU pipe, not DS): x += lane-permuted x.
template <int CTRL>
__device__ __forceinline__ float dpp_add(float x) {
    union { float f; int i; } u, v;
    u.f = x;
    v.i = __builtin_amdgcn_update_dpp(0, u.i, CTRL, 0xF, 0xF, true);
    return x + v.f;
}

// x[l] + x[l^32] in every lane, via v_permlane32_swap (VALU pipe).
__device__ __forceinline__ float permlane32_sum(float x) {
    union { float f; unsigned u; } a; a.f = x;
    u32x2 r = __builtin_amdgcn_permlane32_swap(a.u, a.u, false, false);
    union { unsigned u; float f; } b0, b1;
    b0.u = r[0]; b1.u = r[1];
    return b0.f + b1.f;
}

// ---------------------------------------------------------------------------
// Kernel A (fused prep+pos): one wave per pair (i, i+BHALF).
//  - fp32 sq-norms for both rows (exact), bf16 copy of both rows,
//  - positive-pair term written to posPart[block] (no atomics),
//  - block 0 zeroes out[0] and the 64 group counters.
// ---------------------------------------------------------------------------
__global__ __launch_bounds__(256) void k_prep_pos(const float* __restrict__ F,
                                                  __bf16* __restrict__ Fbf,
                                                  float* __restrict__ sq,
                                                  float* __restrict__ posPart,
                                                  unsigned* __restrict__ cnt,
                                                  float* __restrict__ out) {
    int t = threadIdx.x;
    int w = t >> 6, l = t & 63;
    int p = blockIdx.x * 4 + w;          // pair index 0..4095
    const float2* r1 = (const float2*)(F + (size_t)p * KDIM);
    const float2* r2 = (const float2*)(F + (size_t)(p + BHALF) * KDIM);
    float2 a = r1[l];
    float2 c = r2[l];

    if (blockIdx.x == 0 && t < 64) cnt[t] = 0u;

    float s1 = fmaf(a.x, a.x, a.y * a.y);
    float s2 = fmaf(c.x, c.x, c.y * c.y);
    float dp = fmaf(a.x, c.x, a.y * c.y);
#pragma unroll
    for (int off = 32; off > 0; off >>= 1) {
        s1 += __shfl_down(s1, off);
        s2 += __shfl_down(s2, off);
        dp += __shfl_down(dp, off);
    }

    bf16x2 pa, pc;
    pa[0] = (__bf16)a.x; pa[1] = (__bf16)a.y;
    pc[0] = (__bf16)c.x; pc[1] = (__bf16)c.y;
    ((bf16x2*)(Fbf + (size_t)p * KDIM))[l] = pa;
    ((bf16x2*)(Fbf + (size_t)(p + BHALF) * KDIM))[l] = pc;

    __shared__ float posRed[4];
    if (l == 0) {
        sq[p] = s1;
        sq[p + BHALF] = s2;
        float d2 = fmaxf(s1 + s2 - 2.0f * dp, 0.0f);
        posRed[w] = logf(1.0f + d2);
    }
    __syncthreads();
    if (t == 0) {
        posPart[blockIdx.x] = posRed[0] + posRed[1] + posRed[2] + posRed[3];
        if (blockIdx.x == 0) out[0] = 0.0f;
    }
}

// ---------------------------------------------------------------------------
// Kernel B: MFMA pairwise Cauchy row/col sums, 128x128 tiles + FUSED FINAL.
// 512 persistent blocks; block b owns a CONTIGUOUS chunk of 4-5 triangular
// tiles. A panel re-staged only when ti changes; diag tiles alias A panel.
// Row butterfly on DPP (VALU); col kb-reduce via permlane32_swap (VALU) with
// 8 partials/col in LDS — zero DS-pipe shuffle ops in the epilogue.
// Deterministic Tpart scatter (no atomics): tile (ti,tj) -> row sums to
// slot tj (group ti), col sums to slot ti (group tj); each group needs
// exactly 64 contributions. At block end: release __threadfence + counter
// atomics; the block that completes a group acquire-fences and reduces its
// 64 slots + pos partials -> one atomicAdd(out) per group (64 total).
// k_final is GONE -> one fewer dispatch + graph gap.
// ---------------------------------------------------------------------------
__global__ __launch_bounds__(512, 4) void k_pairwise(
        const __bf16* __restrict__ Fbf,
        const float* __restrict__ sq,
        float* __restrict__ Tpart,
        const float* __restrict__ posPart,
        unsigned* __restrict__ cnt,
        float* __restrict__ out) {
    __shared__ __align__(16) __bf16 As[128 * 128];
    __shared__ __align__(16) __bf16 Bs[128 * 128];
    __shared__ float rowAcc[128][2];
    __shared__ float colAcc[128][8];
    __shared__ int finList[12];
    __shared__ int nFin;
    __shared__ float red2[2];

    int t = threadIdx.x;
    int w = t >> 6;              // wave 0..7
    int l = t & 63;
    int wr = w >> 1, wc = w & 1; // 4x2 wave grid
    int low = l & 15, kb = l >> 4;

    // contiguous chunk: blocks 0..31 own 5 tiles, rest own 4 (32*5+480*4=2080)
    int bid = blockIdx.x;
    int start = bid * 4 + (bid < 32 ? bid : 32);
    int cnt_n = (bid < 32) ? 5 : 4;

    // decode start -> (ti, tj) on the 64x64 upper triangle
    int ti = (int)floorf((129.0f - sqrtf(16641.0f - 8.0f * (float)start)) * 0.5f);
    while (ti * (129 - ti) / 2 > start) --ti;
    while ((ti + 1) * (128 - ti) / 2 <= start) ++ti;
    int tj = ti + (start - ti * (129 - ti) / 2);
    int ti0 = ti, tj0 = tj;

    // stage one 128x128 bf16 tile (2048 16B granules, XOR-swizzled source)
    auto stage = [&](const __bf16* src, __bf16* dst) {
#pragma unroll
        for (int it = 0; it < 4; ++it) {
            int f = it * 512 + t;            // granule slot 0..2047
            int row = f >> 4;
            int sg = f & 15;
            int g = sg ^ (row & 15);         // global granule landing here
            GLOAD_LDS16(src + row * KDIM + g * 8, dst + (size_t)f * 8);
        }
    };

    int curTi = -1;
#pragma unroll 1
    for (int n = 0; n < cnt_n; ++n) {
        int I = ti * 128, J = tj * 128;
        bool diag = (ti == tj);

        // ---- stage tiles; skip A if panel unchanged ----
        if (ti != curTi) {
            stage(Fbf + (size_t)I * KDIM, As);
            curTi = ti;
        }
        if (!diag) {
            stage(Fbf + (size_t)J * KDIM, Bs);
        }
        __syncthreads();

        // ---- MFMA K-loop: 4 steps of K=32, 2x4 fragments per wave ----
        const bf16x8* Asg = (const bf16x8*)As;
        const bf16x8* Bsg = diag ? (const bf16x8*)As : (const bf16x8*)Bs;
        f32x4 acc[2][4] = {};
#pragma unroll
        for (int s = 0; s < 4; ++s) {
            int g = s * 4 + kb;
            bf16x8 aF[2], bF[4];
#pragma unroll
            for (int fr = 0; fr < 2; ++fr) {
                int R = wr * 32 + fr * 16 + low;
                aF[fr] = Asg[R * 16 + (g ^ low)];
            }
#pragma unroll
            for (int fc = 0; fc < 4; ++fc) {
                int C = wc * 64 + fc * 16 + low;
                bF[fc] = Bsg[C * 16 + (g ^ low)];
            }
#pragma unroll
            for (int fr = 0; fr < 2; ++fr)
#pragma unroll
                for (int fc = 0; fc < 4; ++fc)
                    acc[fr][fc] = __builtin_amdgcn_mfma_f32_16x16x32_bf16(
                        aF[fr], bF[fc], acc[fr][fc], 0, 0, 0);
        }

        // ---- epilogue: Cauchy + row/col partial sums ----
        // C/D layout: col = low, row = kb*4 + reg (within each 16x16 frag)
        // 1/(1 + max(d2,0)) = 1/max((1+sqi)+sqj-2acc, 1)  -> fold the +1.
        float sqi1[2][4], sqj[4];
#pragma unroll
        for (int fr = 0; fr < 2; ++fr)
#pragma unroll
            for (int r = 0; r < 4; ++r)
                sqi1[fr][r] = 1.0f + sq[I + wr * 32 + fr * 16 + kb * 4 + r];
#pragma unroll
        for (int fc = 0; fc < 4; ++fc)
            sqj[fc] = sq[J + wc * 64 + fc * 16 + low];

        f32x4 rowPart[2] = {};
        float colPart[4] = {0.f, 0.f, 0.f, 0.f};
#pragma unroll
        for (int fr = 0; fr < 2; ++fr) {
#pragma unroll
            for (int fc = 0; fc < 4; ++fc) {
                f32x4 vv;
#pragma unroll
                for (int r = 0; r < 4; ++r) {
                    float d2 = fmaf(acc[fr][fc][r], -2.0f,
                                    sqi1[fr][r] + sqj[fc]);
                    vv[r] = __builtin_amdgcn_rcpf(fmaxf(d2, 1.0f));
                }
                rowPart[fr] += vv;               // v_pk_add_f32 pairs
                colPart[fc] += (vv[0] + vv[1]) + (vv[2] + vv[3]);
            }
        }

        // row partials: 16-lane butterfly on the VALU via DPP (no DS ops)
#pragma unroll
        for (int fr = 0; fr < 2; ++fr)
#pragma unroll
            for (int r = 0; r < 4; ++r) {
                float x = rowPart[fr][r];
                x = dpp_add<0xB1>(x);    // xor 1 (quad_perm 1,0,3,2)
                x = dpp_add<0x4E>(x);    // xor 2 (quad_perm 2,3,0,1)
                x = dpp_add<0x141>(x);   // xor 4 (row_half_mirror)
                x = dpp_add<0x140>(x);   // xor 8 (row_mirror)
                if (low == 0)
                    rowAcc[wr * 32 + fr * 16 + kb * 4 + r][wc] = x;
            }

        // col partials: kb-pair reduce via permlane32_swap (VALU);
        // lanes l<32 store 2 partials per wave-col, scatter sums 8.
#pragma unroll
        for (int fc = 0; fc < 4; ++fc) {
            float x = permlane32_sum(colPart[fc]);   // x[l] = p[l]+p[l^32]
            if (l < 32)
                colAcc[wc * 64 + fc * 16 + low][wr * 2 + kb] = x;
        }
        __syncthreads();

        // deterministic scatter: slot tj <- rows of panel ti (group ti);
        // slot ti <- cols of panel tj (group tj). Each slot written once.
        if (t < 128) {
            Tpart[tj * N_TOTAL + I + t] = rowAcc[t][0] + rowAcc[t][1];
        } else if (t < 256 && !diag) {
            int c = t - 128;
            const float* ca = colAcc[c];
            Tpart[ti * N_TOTAL + J + c] =
                ((ca[0] + ca[1]) + (ca[2] + ca[3])) +
                ((ca[4] + ca[5]) + (ca[6] + ca[7]));
        }

        // advance to next triangular tile
        ++tj;
        if (tj == NTILE) { ++ti; tj = ti; }
    }

    // ================= fused finale (decoupled last-contributor) ===========
    __syncthreads();       // all waves' scatter stores complete (vmcnt drain)
    __threadfence();       // release: Tpart visible device-wide
    if (t == 0) {
        int nf = 0;
        int a = ti0, b = tj0;
        for (int n = 0; n < cnt_n; ++n) {
            unsigned c = atomicAdd(&cnt[a], 1u);       // row contribution
            if (c == 63u) finList[nf++] = a;
            if (a != b) {
                c = atomicAdd(&cnt[b], 1u);            // col contribution
                if (c == 63u) finList[nf++] = b;
            }
            ++b; if (b == NTILE) { ++a; b = a; }
        }
        nFin = nf;
    }
    __syncthreads();
    int nf = nFin;
    if (nf == 0) return;
    __threadfence();       // acquire: invalidate stale caches before reading

    int e = t & 127, q = t >> 7;
#pragma unroll 1
    for (int f = 0; f < nf; ++f) {
        int g = finList[f];
        const float* col = Tpart + (size_t)g * 128 + e;
        float s = 0.f;
#pragma unroll
        for (int k = 0; k < 16; ++k)
            s += col[(size_t)(q * 16 + k) * N_TOTAL];
        colAcc[e][q] = s;                      // reuse colAcc as scratch
        __syncthreads();
        float v = 0.f;
        if (t < 128) {
            float ssum = colAcc[t][0] + colAcc[t][1] +
                         colAcc[t][2] + colAcc[t][3];
            v = logf(ssum - 1.0f);
            if (t < 32 && g < 32)
                v += 2.0f * posPart[g * 32 + t];   // *2 cancels /(2b)
#pragma unroll
            for (int off = 32; off > 0; off >>= 1) v += __shfl_down(v, off);
            if ((t & 63) == 0) red2[t >> 6] = v;
        }
        __syncthreads();
        if (t == 0)
            atomicAdd(out, (red2[0] + red2[1]) * (1.0f / (2.0f * (float)BHALF)));
        __syncthreads();   // colAcc/red2 reuse safe for next group
    }
}

// ---------------------------------------------------------------------------
extern "C" void kernel_launch(void* const* d_in, const int* in_sizes, int n_in,
                              void* d_out, int out_size, void* d_ws, size_t ws_size,
                              hipStream_t stream) {
    const float* F = (const float*)d_in[0];
    float* out = (float*)d_out;

    char* ws = (char*)d_ws;
    __bf16* Fbf     = (__bf16*)ws;                                 // 2 MB
    float*  sq      = (float*)(ws + (size_t)N_TOTAL * KDIM * 2);   // 32 KB
    float*  posPart = sq + N_TOTAL;                                // 4 KB
    float*  Tpart   = posPart + 1024;                              // 2 MB
    unsigned* cnt   = (unsigned*)(Tpart + (size_t)NTILE * N_TOTAL);// 256 B

    k_prep_pos<<<BHALF / 4, 256, 0, stream>>>(F, Fbf, sq, posPart, cnt, out);
    k_pairwise<<<NBLK_PW, 512, 0, stream>>>(Fbf, sq, Tpart, posPart, cnt, out);
}

// Round 10
// 82.795 us; speedup vs baseline: 2.0116x; 2.0116x over previous
//
#include <hip/hip_runtime.h>
#include <math.h>

#define N_TOTAL 8192
#define BHALF   4096
#define KDIM    128
#define NTILE   64          // 8192 / 128 tile grid
#define NTRI    2080        // 64*65/2 triangular tiles
#define NBLK_PW 512         // persistent blocks, exactly 2 per CU

typedef __bf16 bf16x8 __attribute__((ext_vector_type(8)));
typedef __bf16 bf16x2 __attribute__((ext_vector_type(2)));
typedef float  f32x4  __attribute__((ext_vector_type(4)));

// async global->LDS, 16B per lane; LDS dest must be lane-contiguous.
#define GLOAD_LDS16(GSRC, LDST)                                                \
    __builtin_amdgcn_global_load_lds(                                          \
        (const __attribute__((address_space(1))) void*)(GSRC),                 \
        (__attribute__((address_space(3))) void*)(LDST), 16, 0, 0)

// butterfly-add via DPP (VALU pipe, not DS): x += lane-permuted x.
// 0xB1 = quad_perm(1,0,3,2) -> xor1 ; 0x4E = quad_perm(2,3,0,1) -> xor2 ;
// 0x141 = row_half_mirror -> xor-within-8 ; 0x140 = row_mirror -> xor-within-16.
template <int CTRL>
__device__ __forceinline__ float dpp_add(float x) {
    union { float f; int i; } u, v;
    u.f = x;
    v.i = __builtin_amdgcn_update_dpp(0, u.i, CTRL, 0xF, 0xF, true);
    return x + v.f;
}

// ---------------------------------------------------------------------------
// Kernel A (fused prep+pos): one wave per pair (i, i+BHALF).
//  - fp32 sq-norms for both rows (exact), bf16 copy of both rows,
//  - positive-pair term written to posPart[block] (no atomics),
//  - block 0 zeroes out[0].
// ---------------------------------------------------------------------------
__global__ __launch_bounds__(256) void k_prep_pos(const float* __restrict__ F,
                                                  __bf16* __restrict__ Fbf,
                                                  float* __restrict__ sq,
                                                  float* __restrict__ posPart,
                                                  float* __restrict__ out) {
    int t = threadIdx.x;
    int w = t >> 6, l = t & 63;
    int p = blockIdx.x * 4 + w;          // pair index 0..4095
    const float2* r1 = (const float2*)(F + (size_t)p * KDIM);
    const float2* r2 = (const float2*)(F + (size_t)(p + BHALF) * KDIM);
    float2 a = r1[l];
    float2 c = r2[l];

    float s1 = fmaf(a.x, a.x, a.y * a.y);
    float s2 = fmaf(c.x, c.x, c.y * c.y);
    float dp = fmaf(a.x, c.x, a.y * c.y);
#pragma unroll
    for (int off = 32; off > 0; off >>= 1) {
        s1 += __shfl_down(s1, off);
        s2 += __shfl_down(s2, off);
        dp += __shfl_down(dp, off);
    }

    bf16x2 pa, pc;
    pa[0] = (__bf16)a.x; pa[1] = (__bf16)a.y;
    pc[0] = (__bf16)c.x; pc[1] = (__bf16)c.y;
    ((bf16x2*)(Fbf + (size_t)p * KDIM))[l] = pa;
    ((bf16x2*)(Fbf + (size_t)(p + BHALF) * KDIM))[l] = pc;

    __shared__ float posRed[4];
    if (l == 0) {
        sq[p] = s1;
        sq[p + BHALF] = s2;
        float d2 = fmaxf(s1 + s2 - 2.0f * dp, 0.0f);
        posRed[w] = logf(1.0f + d2);
    }
    __syncthreads();
    if (t == 0) {
        posPart[blockIdx.x] = posRed[0] + posRed[1] + posRed[2] + posRed[3];
        if (blockIdx.x == 0) out[0] = 0.0f;
    }
}

// ---------------------------------------------------------------------------
// Kernel B: MFMA pairwise Cauchy row/col sums, 128x128 tiles.
// 512 persistent blocks; block b owns a CONTIGUOUS chunk of 4-5 triangular
// tiles (row-major in (ti,tj)). A panel is re-staged only when ti changes;
// diagonal tiles read the B operand straight from the A panel (no B stage).
// NO atomics: tile (ti,tj) writes row sums to Tpart[tj][I..I+127] and col
// sums to Tpart[ti][J..J+127] — each (slot, element) written exactly once.
// Row-sum 16-lane butterfly runs on DPP (VALU) instead of ds_bpermute,
// keeping the DS pipe free for ds_read_b128 + staging writes.
// ---------------------------------------------------------------------------
__global__ __launch_bounds__(512, 4) void k_pairwise(
        const __bf16* __restrict__ Fbf,
        const float* __restrict__ sq,
        float* __restrict__ Tpart) {
    __shared__ __align__(16) __bf16 As[128 * 128];
    __shared__ __align__(16) __bf16 Bs[128 * 128];
    __shared__ float rowAcc[128][2];
    __shared__ float colAcc[128][4];

    int t = threadIdx.x;
    int w = t >> 6;              // wave 0..7
    int l = t & 63;
    int wr = w >> 1, wc = w & 1; // 4x2 wave grid
    int low = l & 15, kb = l >> 4;

    // contiguous chunk: blocks 0..31 own 5 tiles, rest own 4 (32*5+480*4=2080)
    int bid = blockIdx.x;
    int start = bid * 4 + (bid < 32 ? bid : 32);
    int cnt = (bid < 32) ? 5 : 4;

    // decode start -> (ti, tj) on the 64x64 upper triangle
    int ti = (int)floorf((129.0f - sqrtf(16641.0f - 8.0f * (float)start)) * 0.5f);
    while (ti * (129 - ti) / 2 > start) --ti;
    while ((ti + 1) * (128 - ti) / 2 <= start) ++ti;
    int tj = ti + (start - ti * (129 - ti) / 2);

    // stage one 128x128 bf16 tile (2048 16B granules, XOR-swizzled source)
    auto stage = [&](const __bf16* src, __bf16* dst) {
#pragma unroll
        for (int it = 0; it < 4; ++it) {
            int f = it * 512 + t;            // granule slot 0..2047
            int row = f >> 4;
            int sg = f & 15;
            int g = sg ^ (row & 15);         // global granule landing here
            GLOAD_LDS16(src + row * KDIM + g * 8, dst + (size_t)f * 8);
        }
    };

    int curTi = -1;
#pragma unroll 1
    for (int n = 0; n < cnt; ++n) {
        int I = ti * 128, J = tj * 128;
        bool diag = (ti == tj);

        // ---- stage tiles; skip A if panel unchanged ----
        if (ti != curTi) {
            stage(Fbf + (size_t)I * KDIM, As);
            curTi = ti;
        }
        if (!diag) {
            stage(Fbf + (size_t)J * KDIM, Bs);
        }
        __syncthreads();

        // ---- MFMA K-loop: 4 steps of K=32, 2x4 fragments per wave ----
        const bf16x8* Asg = (const bf16x8*)As;
        const bf16x8* Bsg = diag ? (const bf16x8*)As : (const bf16x8*)Bs;
        f32x4 acc[2][4] = {};
#pragma unroll
        for (int s = 0; s < 4; ++s) {
            int g = s * 4 + kb;
            bf16x8 aF[2], bF[4];
#pragma unroll
            for (int fr = 0; fr < 2; ++fr) {
                int R = wr * 32 + fr * 16 + low;
                aF[fr] = Asg[R * 16 + (g ^ low)];
            }
#pragma unroll
            for (int fc = 0; fc < 4; ++fc) {
                int C = wc * 64 + fc * 16 + low;
                bF[fc] = Bsg[C * 16 + (g ^ low)];
            }
#pragma unroll
            for (int fr = 0; fr < 2; ++fr)
#pragma unroll
                for (int fc = 0; fc < 4; ++fc)
                    acc[fr][fc] = __builtin_amdgcn_mfma_f32_16x16x32_bf16(
                        aF[fr], bF[fc], acc[fr][fc], 0, 0, 0);
        }

        // ---- epilogue: Cauchy + row/col partial sums ----
        // C/D layout: col = low, row = kb*4 + reg (within each 16x16 frag)
        // 1/(1 + max(d2,0)) = 1/max((1+sqi)+sqj-2acc, 1)  -> fold the +1.
        float sqi1[2][4], sqj[4];
#pragma unroll
        for (int fr = 0; fr < 2; ++fr)
#pragma unroll
            for (int r = 0; r < 4; ++r)
                sqi1[fr][r] = 1.0f + sq[I + wr * 32 + fr * 16 + kb * 4 + r];
#pragma unroll
        for (int fc = 0; fc < 4; ++fc)
            sqj[fc] = sq[J + wc * 64 + fc * 16 + low];

        f32x4 rowPart[2] = {};
        float colPart[4] = {0.f, 0.f, 0.f, 0.f};
#pragma unroll
        for (int fr = 0; fr < 2; ++fr) {
#pragma unroll
            for (int fc = 0; fc < 4; ++fc) {
                f32x4 vv;
#pragma unroll
                for (int r = 0; r < 4; ++r) {
                    float d2 = fmaf(acc[fr][fc][r], -2.0f,
                                    sqi1[fr][r] + sqj[fc]);
                    vv[r] = __builtin_amdgcn_rcpf(fmaxf(d2, 1.0f));
                }
                rowPart[fr] += vv;               // v_pk_add_f32 pairs
                colPart[fc] += (vv[0] + vv[1]) + (vv[2] + vv[3]);
            }
        }

        // row partials: 16-lane butterfly on the VALU via DPP (no DS ops)
#pragma unroll
        for (int fr = 0; fr < 2; ++fr)
#pragma unroll
            for (int r = 0; r < 4; ++r) {
                float x = rowPart[fr][r];
                x = dpp_add<0xB1>(x);    // xor 1 (quad_perm 1,0,3,2)
                x = dpp_add<0x4E>(x);    // xor 2 (quad_perm 2,3,0,1)
                x = dpp_add<0x141>(x);   // xor 4 (row_half_mirror)
                x = dpp_add<0x140>(x);   // xor 8 (row_mirror)
                if (low == 0)
                    rowAcc[wr * 32 + fr * 16 + kb * 4 + r][wc] = x;
            }

        // col partials: reduce across the 4 lane-quads (kb)
#pragma unroll
        for (int fc = 0; fc < 4; ++fc) {
            float x = colPart[fc];
            x += __shfl_xor(x, 16);
            x += __shfl_xor(x, 32);
            if (kb == 0)
                colAcc[wc * 64 + fc * 16 + low][wr] = x;
        }
        __syncthreads();

        // deterministic scatter instead of atomics:
        // slot tj holds row-contribs of panel ti; slot ti holds col-contribs
        // of panel tj. For any element, slots 0..63 are each written once.
        if (t < 128) {
            Tpart[tj * N_TOTAL + I + t] = rowAcc[t][0] + rowAcc[t][1];
        } else if (t < 256 && !diag) {
            int c = t - 128;
            Tpart[ti * N_TOTAL + J + c] =
                colAcc[c][0] + colAcc[c][1] + colAcc[c][2] + colAcc[c][3];
        }

        // advance to next triangular tile
        ++tj;
        if (tj == NTILE) { ++ti; tj = ti; }
    }
}

// ---------------------------------------------------------------------------
// Kernel C: neg term. 32 blocks x 256 threads; thread i column-reduces the
// 64 Tpart slots (fully coalesced), takes log(T-1); lanes <32 also fold the
// pos partials; block-reduce; one atomicAdd into out per block (32 total).
// ---------------------------------------------------------------------------
__global__ __launch_bounds__(256) void k_final(const float* __restrict__ Tpart,
                                               const float* __restrict__ posPart,
                                               float* __restrict__ out) {
    int t = threadIdx.x;
    int i = blockIdx.x * 256 + t;
    float s = 0.0f;
#pragma unroll 8
    for (int k = 0; k < NTILE; ++k) s += Tpart[k * N_TOTAL + i];
    float v = logf(s - 1.0f);
    if (t < 32) v += 2.0f * posPart[blockIdx.x * 32 + t];  // *2 cancels /(2b)
#pragma unroll
    for (int off = 32; off > 0; off >>= 1) v += __shfl_down(v, off);
    __shared__ float red[4];
    int w = t >> 6, l = t & 63;
    if (l == 0) red[w] = v;
    __syncthreads();
    if (t == 0) {
        float S = red[0] + red[1] + red[2] + red[3];
        atomicAdd(out, S * (1.0f / (2.0f * (float)BHALF)));
    }
}

// ---------------------------------------------------------------------------
extern "C" void kernel_launch(void* const* d_in, const int* in_sizes, int n_in,
                              void* d_out, int out_size, void* d_ws, size_t ws_size,
                              hipStream_t stream) {
    const float* F = (const float*)d_in[0];
    float* out = (float*)d_out;

    char* ws = (char*)d_ws;
    __bf16* Fbf     = (__bf16*)ws;                                 // 2 MB
    float*  sq      = (float*)(ws + (size_t)N_TOTAL * KDIM * 2);   // 32 KB
    float*  posPart = sq + N_TOTAL;                                // 4 KB
    float*  Tpart   = posPart + 1024;                              // 2 MB

    k_prep_pos<<<BHALF / 4, 256, 0, stream>>>(F, Fbf, sq, posPart, out);
    k_pairwise<<<NBLK_PW, 512, 0, stream>>>(Fbf, sq, Tpart);
    k_final<<<N_TOTAL / 256, 256, 0, stream>>>(Tpart, posPart, out);
}